// Round 8
// baseline (242.328 us; speedup 1.0000x reference)
//
#include <hip/hip_runtime.h>
#include <hip/hip_fp16.h>

// AdderNet forward:  x[256,1,64,64] -> adder(w1)+BN+ReLU -> adder(w2)+BN+ReLU
//                    -> avgpool -> FC -> out[256,10]
// R13: fused single kernel via SOFTWARE global barrier (no cooperative API).
//   - R12 (hipLaunchCooperativeKernel, 512 blocks) produced out==0: launch
//     never executed (too-large or capture rejection). Same fusion, robust
//     mechanics: regular launch, 256 blocks x 1024 thr, atomic-counter
//     barrier with BOUNDED spin (hang degrades to wrong-answer).
//   - Block b owns IMAGE b end-to-end: phase A writes all of y1[b], phase B
//     consumes it (XCD-L2 local) + writes a2[b], phase C pools its own a2
//     into LDS, phase D does the FC row. Only cross-block data: s1/s2 BN
//     stats (96 doubles, device-scope atomics) + w2b -> TWO barriers only.
//   - Intermediates (~100MB) fit the 256MB LLC: near-zero HBM traffic.
//   - Phase B = verified R10 mqsad core; 16 waves = 2 independent 8-wave
//     halves on 2 bands / 2 LDS tiles (=R10's best 16-waves/CU regime).
//   - launch_bounds(1024,4): VGPR<=128; LDS 28.7KB => >=2 blocks/CU capacity
//     for 1 needed: 2x co-residency margin.

#define HW 4096

typedef unsigned int u32;
typedef unsigned long long u64;
typedef __attribute__((ext_vector_type(4))) unsigned int u32x4;

__device__ __forceinline__ u32x4 mqsad(u64 src, u32 ref, u32x4 acc) {
#if __has_builtin(__builtin_amdgcn_mqsad_u32_u8)
  return __builtin_amdgcn_mqsad_u32_u8(src, ref, acc);
#else
  u32x4 d;
  asm("v_mqsad_u32_u8 %0, %1, %2, %3"
      : "=&v"(d)
      : "v"(src), "v"(ref), "v"(acc));
  return d;
#endif
}

// software grid barrier: arrive (release) + bounded spin (acquire).
__device__ __forceinline__ void gbar(u32* ctr, u32 tgt) {
  __syncthreads();
  if (threadIdx.x == 0) {
    __threadfence();  // release: drain stores to coherent point
    __hip_atomic_fetch_add(ctr, 1u, __ATOMIC_ACQ_REL, __HIP_MEMORY_SCOPE_AGENT);
    u32 n = 0;
    while (__hip_atomic_load(ctr, __ATOMIC_ACQUIRE, __HIP_MEMORY_SCOPE_AGENT) < tgt &&
           ++n < (1u << 21)) {
      __builtin_amdgcn_s_sleep(2);
    }
    __threadfence();  // acquire: invalidate caches before dependent reads
  }
  __syncthreads();
}

__global__ __launch_bounds__(1024, 4) void k_fused(
    const float* __restrict__ x, const float* __restrict__ w1,
    const float* __restrict__ g1, const float* __restrict__ b1,
    const float* __restrict__ w2, const float* __restrict__ g2,
    const float* __restrict__ b2, const float* __restrict__ fw,
    const float* __restrict__ fb, float* __restrict__ out,
    double* s1, double* s2, u32* ctr, u32* w2b,
    __half* __restrict__ y1, __half* __restrict__ a2) {
  __shared__ __align__(16) unsigned char smem[25600];  // A: sx(4752B) B: 2 shu tiles
  __shared__ float red[512];
  __shared__ float p1a[16], p1b[16], p2a[32], p2b[32], poolv[32];
  int blk = blockIdx.x, tid = threadIdx.x;
  int b = blk;  // block owns image b

  // ---- Phase P: block 0 packs w2b (u8 weights, 3 dwords per (og,c,o)) ----
  if (blk == 0 && tid < 512) {
    int oc = tid >> 4, c = tid & 15;
    int og = oc >> 3, o = oc & 7;
    const float* wp = w2 + (oc * 16 + c) * 9;
    u32 q[9];
#pragma unroll
    for (int t = 0; t < 9; t++) {
      float qf = rintf(fmaf(wp[t], 32.f, 48.f));
      q[t] = (u32)fminf(fmaxf(qf, 1.f), 255.f);
    }
    u32* dst = w2b + ((og * 16 + c) * 8 + o) * 3;
    dst[0] = q[0] | (q[1] << 8) | (q[2] << 16);
    dst[1] = q[3] | (q[4] << 8) | (q[5] << 16);
    dst[2] = q[6] | (q[7] << 8) | (q[8] << 16);
  }

  // ---- Phase A: layer-1 adder + stats + y1 store (4 quarters of image b) --
  // 16 waves; wave w computes row row0+w; lane = col.
  float tsum[16], tsq[16];
#pragma unroll
  for (int c = 0; c < 16; c++) { tsum[c] = 0.f; tsq[c] = 0.f; }
  {
    int col = tid & 63, wr = tid >> 6;
    const float* xb = x + b * HW;
#pragma unroll 1
    for (int q4 = 0; q4 < 4; q4++) {
      int row0 = q4 * 16;
      float* sx = (float*)smem;
      __syncthreads();  // prior pass done with sx
      for (int i = tid; i < 18 * 66; i += 1024) {
        int rr = i / 66, cc = i - rr * 66;
        int ry = row0 + rr - 1, rx = cc - 1;
        sx[i] = (ry >= 0 && ry < 64 && rx >= 0 && rx < 64) ? xb[ry * 64 + rx] : 0.f;
      }
      __syncthreads();
      float pa[9];
#pragma unroll
      for (int dy = 0; dy < 3; dy++)
#pragma unroll
        for (int dx = 0; dx < 3; dx++)
          pa[dy * 3 + dx] = sx[(wr + dy) * 66 + col + dx];
#pragma unroll
      for (int c = 0; c < 16; c++) {  // FULL unroll: tsum/tsq stay in regs
        float wv[9];
#pragma unroll
        for (int t = 0; t < 9; t++) wv[t] = w1[c * 9 + t];
        float acc = 0.f;
#pragma unroll
        for (int t = 0; t < 9; t++) acc += fabsf(pa[t] - wv[t]);
        float v = -acc;
        tsum[c] += v;
        tsq[c] = fmaf(v, v, tsq[c]);
        y1[(((size_t)(b * 16 + c)) << 12) + ((row0 + wr) << 6) + col] = __float2half(v);
      }
    }
    int lane = tid & 63;
#pragma unroll
    for (int c = 0; c < 16; c++) {
      float s = tsum[c], qv = tsq[c];
      for (int off = 32; off; off >>= 1) {
        s += __shfl_down(s, off, 64);
        qv += __shfl_down(qv, off, 64);
      }
      if (lane == 0) { red[(wr * 16 + c) * 2] = s; red[(wr * 16 + c) * 2 + 1] = qv; }
    }
    __syncthreads();
    if (tid < 16) {
      float s = 0.f, qv = 0.f;
#pragma unroll
      for (int w = 0; w < 16; w++) {
        s += red[(w * 16 + tid) * 2];
        qv += red[(w * 16 + tid) * 2 + 1];
      }
      atomicAdd(&s1[tid], (double)s);
      atomicAdd(&s1[16 + tid], (double)qv);
    }
  }
  gbar(ctr + 0, 256);

  // ---- Phase B: layer 2 (mqsad core); 2 half-blocks x 4 band-pairs -------
  if (tid < 16) {  // BN1 params folded into u8 quant constants
    double N = 1048576.0;
    double mean = s1[tid] / N;
    double var = s1[16 + tid] / N - mean * mean;
    float inv = (float)(1.0 / sqrt(var + 1e-5));
    float sc = g1[tid] * inv;
    float sf = b1[tid] - (float)mean * sc;
    p1a[tid] = sc * 32.f;
    p1b[tid] = fmaf(sf, 32.f, 48.5f);
  }
  __syncthreads();

  {
    int th = tid & 511, hb = tid >> 9;  // half-block: waves 0-7 / 8-15
    int lane = tid & 63;
    int w8 = (tid >> 6) & 7;
    int og = w8 >> 1, half = w8 & 1;
    int wofs = __builtin_amdgcn_readfirstlane(og * 384 + half * 12);
    const u32* wbase = w2b + wofs;
    int r = lane >> 3, x0 = (lane & 7) << 3;
    unsigned char* shu = smem + hb * 12800;
    const unsigned char* shb = shu + r * 80 + x0;

    float ssum[4], ssq[4];
#pragma unroll
    for (int o = 0; o < 4; o++) { ssum[o] = 0.f; ssq[o] = 0.f; }

#pragma unroll 1
    for (int pr = 0; pr < 4; pr++) {
      int y0 = (pr * 2 + hb) * 8;
      __syncthreads();  // shu safe to overwrite

      // stage: y1 fp16 -> BN -> relu -> u8 quant -> LDS [16ch][10r][80]
#pragma unroll 1
      for (int pp = 0; pp < 3; pp++) {
        int jj = pp * 512 + th;
        if (jj < 1280) {
          int rowjob = jj >> 3, kq = jj & 7;
          int ch = rowjob / 10;
          int rr = rowjob - ch * 10;
          int gr = y0 + rr - 1;
          float sc8 = p1a[ch], sf8 = p1b[ch];
          u32 B[8];
          if (gr >= 0 && gr < 64) {
            uint4 v = *reinterpret_cast<const uint4*>(
                y1 + (((size_t)(b * 16 + ch)) << 12) + (gr << 6) + (kq << 3));
            const u32* vd = reinterpret_cast<const u32*>(&v);
#pragma unroll
            for (int qq = 0; qq < 4; qq++) {
              float2 f = __half22float2(*reinterpret_cast<const __half2*>(&vd[qq]));
              float t0 = fmaf(f.x, sc8, sf8);
              float t1 = fmaf(f.y, sc8, sf8);
              B[qq * 2] = (u32)fminf(fmaxf(t0, 48.5f), 255.f);
              B[qq * 2 + 1] = (u32)fminf(fmaxf(t1, 48.5f), 255.f);
            }
          } else {
#pragma unroll
            for (int qq = 0; qq < 8; qq++) B[qq] = 48u;
          }
          u32 prev = (u32)__shfl_up((int)B[7], 1, 64);
          if (kq == 0) prev = 48u;  // image col -1 pad
          u32 d0 = prev | (B[0] << 8) | (B[1] << 16) | (B[2] << 24);
          u32 d1 = B[3] | (B[4] << 8) | (B[5] << 16) | (B[6] << 24);
          unsigned char* dst = shu + rowjob * 80 + (kq << 3);
          *reinterpret_cast<uint2*>(dst) = make_uint2(d0, d1);
          if (kq == 7)  // storage cols 64..67: image col 63, pads
            *reinterpret_cast<u32*>(dst + 8) = B[7] | 0x30303000u;
        }
      }
      __syncthreads();

      // main mqsad loop (R10 core)
      u32x4 acc[4][2];
#pragma unroll
      for (int o = 0; o < 4; o++) { acc[o][0] = (u32x4)(0u); acc[o][1] = (u32x4)(0u); }

      u64 Aa[3], Ab[3];
      u32 Ma[3], Mb[3];
      u32 Wa[12], Wb[12];

#define LOADC(Av, Mv, Wv, cc)                                     \
  do {                                                            \
    const unsigned char* rp_ = shb + (cc) * 800;                  \
    _Pragma("unroll") for (int dy_ = 0; dy_ < 3; dy_++) {         \
      Av[dy_] = *reinterpret_cast<const u64*>(rp_ + dy_ * 80);    \
      Mv[dy_] = *reinterpret_cast<const u32*>(rp_ + dy_ * 80 + 8);\
    }                                                             \
    const u32* wc_ = wbase + (cc) * 24;                           \
    _Pragma("unroll") for (int j_ = 0; j_ < 12; j_++) Wv[j_] = wc_[j_]; \
  } while (0)

#define COMPUTE(Av, Mv, Wv)                                       \
  do {                                                            \
    _Pragma("unroll") for (int dy_ = 0; dy_ < 3; dy_++) {         \
      u64 lo_ = Av[dy_];                                          \
      u64 hi_ = (Av[dy_] >> 32) | ((u64)Mv[dy_] << 32);           \
      _Pragma("unroll") for (int o_ = 0; o_ < 4; o_++) {          \
        u32 wr_ = Wv[o_ * 3 + dy_];                               \
        acc[o_][0] = mqsad(lo_, wr_, acc[o_][0]);                 \
        acc[o_][1] = mqsad(hi_, wr_, acc[o_][1]);                 \
      }                                                           \
    }                                                             \
  } while (0)

      LOADC(Aa, Ma, Wa, 0);
#pragma unroll 1
      for (int c = 0; c < 16; c += 2) {
        LOADC(Ab, Mb, Wb, c + 1);
        COMPUTE(Aa, Ma, Wa);
        if (c < 14) LOADC(Aa, Ma, Wa, c + 2);
        COMPUTE(Ab, Mb, Wb);
      }
#undef LOADC
#undef COMPUTE

      // store (negate + rescale); accumulate stats partials in registers
      const float ksc = -1.f / 32.f;
      __half* a2b =
          a2 + ((size_t)b * 32 + og * 8 + half * 4) * HW + (y0 + r) * 64 + x0;
#pragma unroll
      for (int o = 0; o < 4; o++) {
        float f0 = (float)acc[o][0].x * ksc, f1 = (float)acc[o][0].y * ksc;
        float f2 = (float)acc[o][0].z * ksc, f3 = (float)acc[o][0].w * ksc;
        float f4 = (float)acc[o][1].x * ksc, f5 = (float)acc[o][1].y * ksc;
        float f6 = (float)acc[o][1].z * ksc, f7 = (float)acc[o][1].w * ksc;
        __half2 h01 = __floats2half2_rn(f0, f1);
        __half2 h23 = __floats2half2_rn(f2, f3);
        __half2 h45 = __floats2half2_rn(f4, f5);
        __half2 h67 = __floats2half2_rn(f6, f7);
        uint4 st = make_uint4(*reinterpret_cast<u32*>(&h01), *reinterpret_cast<u32*>(&h23),
                              *reinterpret_cast<u32*>(&h45), *reinterpret_cast<u32*>(&h67));
        *reinterpret_cast<uint4*>(a2b + o * HW) = st;
        float2 c0 = __half22float2(h01), c1 = __half22float2(h23);
        float2 c2 = __half22float2(h45), c3 = __half22float2(h67);
        ssum[o] += c0.x + c0.y + c1.x + c1.y + c2.x + c2.y + c3.x + c3.y;
        ssq[o] += c0.x * c0.x + c0.y * c0.y + c1.x * c1.x + c1.y * c1.y +
                  c2.x * c2.x + c2.y * c2.y + c3.x * c3.x + c3.y * c3.y;
      }
    }

    // stats: wave reduce once, then 32 atomics per block
#pragma unroll
    for (int o = 0; o < 4; o++) {
      float s = ssum[o], qv = ssq[o];
      for (int off = 32; off; off >>= 1) {
        s += __shfl_down(s, off, 64);
        qv += __shfl_down(qv, off, 64);
      }
      if (lane == 0) {
        red[(hb * 8 + w8) * 8 + o * 2] = s;
        red[(hb * 8 + w8) * 8 + o * 2 + 1] = qv;
      }
    }
    __syncthreads();
    if (tid < 32) {  // oc -> wave ww (both halves), slot oo
      int oc = tid;
      int ww = (oc >> 3) * 2 + ((oc >> 2) & 1);
      int oo = oc & 3;
      float s = red[ww * 8 + oo * 2] + red[(8 + ww) * 8 + oo * 2];
      float qv = red[ww * 8 + oo * 2 + 1] + red[(8 + ww) * 8 + oo * 2 + 1];
      atomicAdd(&s2[oc], (double)s);
      atomicAdd(&s2[32 + oc], (double)qv);
    }
  }
  gbar(ctr + 1, 256);

  // ---- Phase C: BN2 + ReLU + avgpool of own image (L2-warm) --------------
  if (tid < 32) {
    double N = 1048576.0;
    double mean = s2[tid] / N;
    double var = s2[32 + tid] / N - mean * mean;
    float inv = (float)(1.0 / sqrt(var + 1e-5));
    float sc = g2[tid] * inv;
    p2a[tid] = sc;
    p2b[tid] = b2[tid] - (float)mean * sc;
  }
  __syncthreads();
  {
    int oc = tid >> 5, part = tid & 31;  // 32 threads per channel
    const uint4* p = (const uint4*)(a2 + ((size_t)b * 32 + oc) * HW);
    float s = p2a[oc], f = p2b[oc];
    float acc = 0.f;
#pragma unroll
    for (int i = 0; i < 16; i++) {  // 16 x 32thr x 8 halves = 4096
      uint4 v = p[i * 32 + part];
      float2 f0 = __half22float2(*reinterpret_cast<const __half2*>(&v.x));
      float2 f1 = __half22float2(*reinterpret_cast<const __half2*>(&v.y));
      float2 f2 = __half22float2(*reinterpret_cast<const __half2*>(&v.z));
      float2 f3 = __half22float2(*reinterpret_cast<const __half2*>(&v.w));
      acc += fmaxf(fmaf(f0.x, s, f), 0.f) + fmaxf(fmaf(f0.y, s, f), 0.f) +
             fmaxf(fmaf(f1.x, s, f), 0.f) + fmaxf(fmaf(f1.y, s, f), 0.f) +
             fmaxf(fmaf(f2.x, s, f), 0.f) + fmaxf(fmaf(f2.y, s, f), 0.f) +
             fmaxf(fmaf(f3.x, s, f), 0.f) + fmaxf(fmaf(f3.y, s, f), 0.f);
    }
    acc += __shfl_down(acc, 16, 32);
    acc += __shfl_down(acc, 8, 32);
    acc += __shfl_down(acc, 4, 32);
    acc += __shfl_down(acc, 2, 32);
    acc += __shfl_down(acc, 1, 32);
    if (part == 0) poolv[oc] = acc * (1.f / 4096.f);
  }
  __syncthreads();

  // ---- Phase D: FC row for image b ---------------------------------------
  if (tid < 10) {
    float rr = fb[tid];
#pragma unroll
    for (int oc = 0; oc < 32; oc++) rr += poolv[oc] * fw[tid * 32 + oc];
    out[b * 10 + tid] = rr;
  }
}

extern "C" void kernel_launch(void* const* d_in, const int* in_sizes, int n_in,
                              void* d_out, int out_size, void* d_ws, size_t ws_size,
                              hipStream_t stream) {
  const float* x   = (const float*)d_in[0];
  const float* w1  = (const float*)d_in[1];
  const float* g1  = (const float*)d_in[2];
  const float* b1  = (const float*)d_in[3];
  const float* w2  = (const float*)d_in[4];
  const float* g2  = (const float*)d_in[5];
  const float* b2  = (const float*)d_in[6];
  const float* fcw = (const float*)d_in[7];
  const float* fcb = (const float*)d_in[8];
  float* out = (float*)d_out;

  char* ws = (char*)d_ws;
  __half* a2 = (__half*)ws;                                // 67,108,864 B
  double* stats = (double*)(ws + 67108864);                // 96 doubles
  double* s1 = stats;                                      // sum[16], sq[16]
  double* s2 = stats + 32;                                 // sum[32], sq[32]
  u32* ctr = (u32*)(ws + 67108864 + 768);                  // 2 barrier counters
  u32* w2b = (u32*)(ws + 67108864 + 1024);                 // 1536 dwords
  __half* y1 = (__half*)(ws + 67108864 + 16384);           // 33,554,432 B

  hipMemsetAsync(stats, 0, 1024, stream);  // stats + counters
  k_fused<<<256, 1024, 0, stream>>>(x, w1, g1, b1, w2, g2, b2, fcw, fcb,
                                    out, s1, s2, ctr, w2b, y1, a2);
}